// Round 6
// baseline (185.070 us; speedup 1.0000x reference)
//
#include <hip/hip_runtime.h>
#include <math.h>

#define SEQ   2048
#define HID   1024
#define INTER 2048
#define DST   16
#define DTR   64
#define NP    96   // DTR + 2*DST
#define NC    64   // scan chunks
#define LCH   32   // steps per chunk (NC*LCH == SEQ)
#define KS    16   // split-K factor for h @ W_x

typedef _Float16 f16;
typedef _Float16 f16x8 __attribute__((ext_vector_type(8)));
typedef _Float16 f16x4v __attribute__((ext_vector_type(4)));
typedef float f32x4 __attribute__((ext_vector_type(4)));

__device__ __forceinline__ float sigmoidf_(float x) { return 1.0f / (1.0f + expf(-x)); }
__device__ __forceinline__ float siluf_(float x)    { return x * sigmoidf_(x); }
__device__ __forceinline__ float softplusf_(float x){ return (x > 20.0f) ? x : log1pf(expf(x)); }

// XCD-aware bijective block swizzle (requires nwg % 8 == 0): blocks dispatched
// round-robin over 8 XCDs get contiguous tile ranges -> L2 panel locality.
__device__ __forceinline__ int xcd_swz(int bid, int nwg)
{
    int cpx = nwg >> 3;
    return (bid & 7) * cpx + (bid >> 3);
}

// ---------------------------------------------------------------------------
// prep_all: one kernel doing x->f16 + all 4 weight transposes (f32 -> f16^T).
// Block ranges: [0,2048) cvt x | [2048,6144) W_in | [6144,8192) W_out
//               [8192,8384) W_x | [8384,8512) W_dt
// ---------------------------------------------------------------------------
__device__ __forceinline__ void tile_transpose(const float* __restrict__ W,
                                               f16* __restrict__ Wt,
                                               int K, int N, int bx, int by, int tid)
{
    __shared__ float t[32][33];
    const int n0 = bx * 32, k0 = by * 32;
    const int j = tid & 31, i0 = tid >> 5;   // i0: 0..7
#pragma unroll
    for (int r = 0; r < 4; ++r)
        t[i0 + r * 8][j] = W[(size_t)(k0 + i0 + r * 8) * N + n0 + j];
    __syncthreads();
#pragma unroll
    for (int r = 0; r < 4; ++r)
        Wt[(size_t)(n0 + i0 + r * 8) * K + k0 + j] = (f16)t[j][i0 + r * 8];
}

__global__ __launch_bounds__(256) void prep_all(const float* __restrict__ x,
                                                const float* __restrict__ W_in,
                                                const float* __restrict__ W_out,
                                                const float* __restrict__ W_x,
                                                const float* __restrict__ W_dt,
                                                f16* __restrict__ xh,
                                                f16* __restrict__ W_in_t,
                                                f16* __restrict__ W_out_t,
                                                f16* __restrict__ WxT,
                                                f16* __restrict__ WdtT)
{
    const int bid = blockIdx.x, tid = threadIdx.x;
    if (bid < 2048) {
        int i = (bid * 256 + tid) * 4;
        float4 v = *(const float4*)&x[i];
        f16x4v o;
        o.x = (f16)v.x; o.y = (f16)v.y; o.z = (f16)v.z; o.w = (f16)v.w;
        *(f16x4v*)&xh[i] = o;
    } else if (bid < 6144) {
        int t = bid - 2048;                       // W_in: K=1024, N=4096
        tile_transpose(W_in, W_in_t, HID, 4096, t & 127, t >> 7, tid);
    } else if (bid < 8192) {
        int t = bid - 6144;                       // W_out: K=2048, N=1024
        tile_transpose(W_out, W_out_t, INTER, HID, t & 31, t >> 5, tid);
    } else if (bid < 8384) {
        int t = bid - 8192;                       // W_x: K=2048, N=96
        tile_transpose(W_x, WxT, INTER, NP, t % 3, t / 3, tid);
    } else {
        int t = bid - 8384;                       // W_dt: K=64, N=2048
        tile_transpose(W_dt, WdtT, DTR, INTER, t & 63, t >> 6, tid);
    }
}

// ---------------------------------------------------------------------------
// MFMA f16 GEMM: C[M,N] OutT = Ah[M,K] f16 @ Bt[N,K]^T f16.
// m97 structure: BK=64, 4 waves (2x2), global_load_lds width 16, linear LDS.
// 1D grid + XCD swizzle; nbx = blocks along N.
// ---------------------------------------------------------------------------
template<int BM, int BN, int KK, typename OutT>
__global__ __launch_bounds__(256) void gemm_f16mfma(const f16* __restrict__ Ah,
                                                    const f16* __restrict__ Bt,
                                                    OutT* __restrict__ C,
                                                    int N, int nbx)
{
    constexpr int BK = 64;
    __shared__ __align__(16) f16 As[BM * BK];
    __shared__ __align__(16) f16 Bs[BN * BK];

    const int tile = xcd_swz(blockIdx.x, gridDim.x);
    const int bx = tile % nbx, by = tile / nbx;

    const int tid = threadIdx.x;
    const int wid = tid >> 6, lane = tid & 63;
    const int wr = wid >> 1, wc = wid & 1;
    const int m0 = by * BM, n0 = bx * BN;
    const int l15 = lane & 15, lhi = lane >> 4;

    constexpr int MR = BM / 32;
    constexpr int NR = BN / 32;

    f32x4 acc[MR][NR] = {};

    for (int k0 = 0; k0 < KK; k0 += BK) {
        constexpr int CA = BM * BK * 2 / 1024;
#pragma unroll
        for (int c0 = 0; c0 < CA; c0 += 4) {
            int c = c0 + wid;
            int e = c * 64 + lane;
            int row = e >> 3, seg = e & 7;
            __builtin_amdgcn_global_load_lds(
                (const __attribute__((address_space(1))) unsigned int*)
                    (Ah + (size_t)(m0 + row) * KK + k0 + seg * 8),
                (__attribute__((address_space(3))) unsigned int*)(As + c * 512),
                16, 0, 0);
        }
        constexpr int CB = BN * BK * 2 / 1024;
#pragma unroll
        for (int c0 = 0; c0 < CB; c0 += 4) {
            int c = c0 + wid;
            int e = c * 64 + lane;
            int row = e >> 3, seg = e & 7;
            __builtin_amdgcn_global_load_lds(
                (const __attribute__((address_space(1))) unsigned int*)
                    (Bt + (size_t)(n0 + row) * KK + k0 + seg * 8),
                (__attribute__((address_space(3))) unsigned int*)(Bs + c * 512),
                16, 0, 0);
        }
        __syncthreads();

#pragma unroll
        for (int kk = 0; kk < BK; kk += 32) {
            f16x8 af[MR], bf[NR];
#pragma unroll
            for (int i = 0; i < MR; ++i)
                af[i] = *(const f16x8*)&As[(wr * (BM / 2) + i * 16 + l15) * BK + kk + lhi * 8];
#pragma unroll
            for (int n = 0; n < NR; ++n)
                bf[n] = *(const f16x8*)&Bs[(wc * (BN / 2) + n * 16 + l15) * BK + kk + lhi * 8];
#pragma unroll
            for (int i = 0; i < MR; ++i)
#pragma unroll
                for (int n = 0; n < NR; ++n)
                    acc[i][n] = __builtin_amdgcn_mfma_f32_16x16x32_f16(af[i], bf[n], acc[i][n], 0, 0, 0);
        }
        __syncthreads();
    }

    // C/D map: col = lane&15, row = (lane>>4)*4 + reg
#pragma unroll
    for (int i = 0; i < MR; ++i)
#pragma unroll
        for (int n = 0; n < NR; ++n)
#pragma unroll
            for (int r = 0; r < 4; ++r)
                C[(size_t)(m0 + wr * (BM / 2) + i * 16 + lhi * 4 + r) * N
                  + n0 + wc * (BN / 2) + n * 16 + l15] = (OutT)acc[i][n][r];
}

// ---------------------------------------------------------------------------
// h @ W_x split-K MFMA: partials[ks][SEQ][96] (f16) = h[:,ks*128:+128] @ WxT^T
// ---------------------------------------------------------------------------
__global__ __launch_bounds__(256) void hwx_mfma(const f16* __restrict__ hh,
                                                const f16* __restrict__ WxT,
                                                f16* __restrict__ partials)
{
    constexpr int BM = 128, BN = 96, BK = 64;
    __shared__ __align__(16) f16 As[BM * BK];
    __shared__ __align__(16) f16 Bs[BN * BK];

    const int tile = xcd_swz(blockIdx.x, gridDim.x);
    const int bxm = tile & 15, ks = tile >> 4;

    const int tid = threadIdx.x;
    const int wid = tid >> 6, lane = tid & 63;
    const int wr = wid >> 1, wc = wid & 1;
    const int m0 = bxm * BM;
    const int l15 = lane & 15, lhi = lane >> 4;

    constexpr int MR = 4, NR = 3;
    f32x4 acc[MR][NR] = {};

    for (int k0 = ks * 128; k0 < ks * 128 + 128; k0 += BK) {
#pragma unroll
        for (int c0 = 0; c0 < 16; c0 += 4) {
            int c = c0 + wid;
            int e = c * 64 + lane;
            int row = e >> 3, seg = e & 7;
            __builtin_amdgcn_global_load_lds(
                (const __attribute__((address_space(1))) unsigned int*)
                    (hh + (size_t)(m0 + row) * INTER + k0 + seg * 8),
                (__attribute__((address_space(3))) unsigned int*)(As + c * 512),
                16, 0, 0);
        }
#pragma unroll
        for (int c0 = 0; c0 < 12; c0 += 4) {
            int c = c0 + wid;
            int e = c * 64 + lane;
            int row = e >> 3, seg = e & 7;
            __builtin_amdgcn_global_load_lds(
                (const __attribute__((address_space(1))) unsigned int*)
                    (WxT + (size_t)row * INTER + k0 + seg * 8),
                (__attribute__((address_space(3))) unsigned int*)(Bs + c * 512),
                16, 0, 0);
        }
        __syncthreads();

#pragma unroll
        for (int kk = 0; kk < BK; kk += 32) {
            f16x8 af[MR], bf[NR];
#pragma unroll
            for (int i = 0; i < MR; ++i)
                af[i] = *(const f16x8*)&As[(wr * 64 + i * 16 + l15) * BK + kk + lhi * 8];
#pragma unroll
            for (int n = 0; n < NR; ++n)
                bf[n] = *(const f16x8*)&Bs[(wc * 48 + n * 16 + l15) * BK + kk + lhi * 8];
#pragma unroll
            for (int i = 0; i < MR; ++i)
#pragma unroll
                for (int n = 0; n < NR; ++n)
                    acc[i][n] = __builtin_amdgcn_mfma_f32_16x16x32_f16(af[i], bf[n], acc[i][n], 0, 0, 0);
        }
        __syncthreads();
    }

    f16* P = partials + (size_t)ks * (SEQ * NP);
#pragma unroll
    for (int i = 0; i < MR; ++i)
#pragma unroll
        for (int n = 0; n < NR; ++n)
#pragma unroll
            for (int r = 0; r < 4; ++r)
                P[(size_t)(m0 + wr * 64 + i * 16 + lhi * 4 + r) * NP
                  + wc * 48 + n * 16 + l15] = (f16)acc[i][n][r];
}

// ---------------------------------------------------------------------------
// reduce 16 f16 partial planes -> ssm_p (B,C cols, f32) + tsh (ts cols, f16).
// 8 elements per thread (f16x8 loads).
// ---------------------------------------------------------------------------
__global__ __launch_bounds__(256) void reduce_partials(const f16* __restrict__ partials,
                                                       float* __restrict__ ssm_p,
                                                       f16* __restrict__ tsh)
{
    int t = blockIdx.x * 256 + threadIdx.x;     // over SEQ*NP/8 = 24576
    int i8 = t * 8;
    int s = i8 / NP, j0 = i8 % NP;
    float a[8] = {};
#pragma unroll
    for (int c = 0; c < KS; ++c) {
        f16x8 v = *(const f16x8*)&partials[(size_t)c * (SEQ * NP) + i8];
#pragma unroll
        for (int j = 0; j < 8; ++j) a[j] += (float)v[j];
    }
    if (j0 < DTR) {
        f16x8 o;
#pragma unroll
        for (int j = 0; j < 8; ++j) o[j] = (f16)a[j];
        *(f16x8*)&tsh[(size_t)s * DTR + j0] = o;
    } else {
        *(float4*)&ssm_p[(size_t)s * NP + j0]     = make_float4(a[0], a[1], a[2], a[3]);
        *(float4*)&ssm_p[(size_t)s * NP + j0 + 4] = make_float4(a[4], a[5], a[6], a[7]);
    }
}

// ---------------------------------------------------------------------------
// dt = softplus(ts @ W_dt + b_dt), f16 MFMA, K=64 single staging iteration.
// ---------------------------------------------------------------------------
__global__ __launch_bounds__(256) void dt_mfma(const f16* __restrict__ tsh,
                                               const f16* __restrict__ WdtT,
                                               const float* __restrict__ bdt,
                                               f16* __restrict__ dtbh)
{
    constexpr int BM = 128, BN = 128, BK = 64;
    __shared__ __align__(16) f16 As[BM * BK];
    __shared__ __align__(16) f16 Bs[BN * BK];

    const int tile = xcd_swz(blockIdx.x, gridDim.x);
    const int bx = tile & 15, by = tile >> 4;

    const int tid = threadIdx.x;
    const int wid = tid >> 6, lane = tid & 63;
    const int wr = wid >> 1, wc = wid & 1;
    const int m0 = by * BM, n0 = bx * BN;
    const int l15 = lane & 15, lhi = lane >> 4;

    constexpr int MR = 4, NR = 4;
    f32x4 acc[MR][NR] = {};

#pragma unroll
    for (int c0 = 0; c0 < 16; c0 += 4) {
        int c = c0 + wid;
        int e = c * 64 + lane;
        int row = e >> 3, seg = e & 7;
        __builtin_amdgcn_global_load_lds(
            (const __attribute__((address_space(1))) unsigned int*)
                (tsh + (size_t)(m0 + row) * DTR + seg * 8),
            (__attribute__((address_space(3))) unsigned int*)(As + c * 512),
            16, 0, 0);
        __builtin_amdgcn_global_load_lds(
            (const __attribute__((address_space(1))) unsigned int*)
                (WdtT + (size_t)(n0 + row) * DTR + seg * 8),
            (__attribute__((address_space(3))) unsigned int*)(Bs + c * 512),
            16, 0, 0);
    }
    __syncthreads();

#pragma unroll
    for (int kk = 0; kk < 64; kk += 32) {
        f16x8 af[MR], bf[NR];
#pragma unroll
        for (int i = 0; i < MR; ++i)
            af[i] = *(const f16x8*)&As[(wr * 64 + i * 16 + l15) * BK + kk + lhi * 8];
#pragma unroll
        for (int n = 0; n < NR; ++n)
            bf[n] = *(const f16x8*)&Bs[(wc * 64 + n * 16 + l15) * BK + kk + lhi * 8];
#pragma unroll
        for (int i = 0; i < MR; ++i)
#pragma unroll
            for (int n = 0; n < NR; ++n)
                acc[i][n] = __builtin_amdgcn_mfma_f32_16x16x32_f16(af[i], bf[n], acc[i][n], 0, 0, 0);
    }

#pragma unroll
    for (int i = 0; i < MR; ++i)
#pragma unroll
        for (int n = 0; n < NR; ++n) {
            int col = n0 + wc * 64 + n * 16 + l15;
            float bv = bdt[col];
#pragma unroll
            for (int r = 0; r < 4; ++r)
                dtbh[(size_t)(m0 + wr * 64 + i * 16 + lhi * 4 + r) * INTER + col] =
                    (f16)softplusf_(acc[i][n][r] + bv);
        }
}

// ---------------------------------------------------------------------------
// Depthwise causal conv (K=4) + bias + SiLU; f16 in (proj raw half), f16 out.
// ---------------------------------------------------------------------------
__global__ __launch_bounds__(256) void conv_silu(const f16* __restrict__ projh,
                                                 const float* __restrict__ cw,
                                                 const float* __restrict__ cb,
                                                 f16* __restrict__ hh)
{
    int idx = blockIdx.x * 256 + threadIdx.x;   // over SEQ*INTER/8
    int c8 = (idx & (INTER / 8 - 1)) * 8;
    int s = idx >> 8;
    float acc[8];
#pragma unroll
    for (int j = 0; j < 8; ++j) acc[j] = cb[c8 + j];
#pragma unroll
    for (int k = 0; k < 4; ++k) {
        int sp = s + k - 3;
        if (sp >= 0) {
            f16x8 p = *(const f16x8*)&projh[(size_t)sp * (2 * INTER) + c8];
#pragma unroll
            for (int j = 0; j < 8; ++j)
                acc[j] = fmaf((float)p[j], cw[k * INTER + c8 + j], acc[j]);
        }
    }
    f16x8 o;
#pragma unroll
    for (int j = 0; j < 8; ++j) o[j] = (f16)siluf_(acc[j]);
    *(f16x8*)&hh[(size_t)idx * 8] = o;
}

// ---------------------------------------------------------------------------
// Chunked parallel scan (pass1/2/3); f16 dt/h/gate inputs, f16 y output.
// ---------------------------------------------------------------------------
__global__ __launch_bounds__(256) void ssm_pass1(const f16* __restrict__ dtbh,
                                                 const f16* __restrict__ hh,
                                                 const float* __restrict__ ssm_p,
                                                 const float* __restrict__ A_log,
                                                 float* __restrict__ Sbuf,
                                                 float* __restrict__ Pbuf)
{
    const int h = blockIdx.x * 256 + threadIdx.x;
    const int c = blockIdx.y;
    const int s0 = c * LCH;

    __shared__ float Bs[LCH][DST];
    for (int j = threadIdx.x; j < LCH * DST; j += 256) {
        int r = j >> 4, dd = j & 15;
        Bs[r][dd] = ssm_p[(size_t)(s0 + r) * NP + DTR + dd];
    }
    __syncthreads();

    float A[DST], st[DST], P[DST];
#pragma unroll
    for (int d = 0; d < DST; ++d) {
        A[d] = -__expf(A_log[(size_t)h * DST + d]);
        st[d] = 0.0f;
        P[d] = 1.0f;
    }

    for (int r = 0; r < LCH; ++r) {
        float dtv = (float)dtbh[(size_t)(s0 + r) * INTER + h];
        float hv  = (float)hh[(size_t)(s0 + r) * INTER + h];
        float dh = dtv * hv;
#pragma unroll
        for (int d = 0; d < DST; ++d) {
            float da = __expf(dtv * A[d]);
            st[d] = fmaf(da, st[d], dh * Bs[r][d]);
            P[d] *= da;
        }
    }

    size_t base = ((size_t)c * INTER + h) * DST;
#pragma unroll
    for (int d = 0; d < DST; d += 4) {
        *(float4*)&Sbuf[base + d] = make_float4(st[d], st[d+1], st[d+2], st[d+3]);
        *(float4*)&Pbuf[base + d] = make_float4(P[d], P[d+1], P[d+2], P[d+3]);
    }
}

__global__ __launch_bounds__(256) void ssm_pass2(const float* __restrict__ Sbuf,
                                                 const float* __restrict__ Pbuf,
                                                 float* __restrict__ Cin)
{
    int i = blockIdx.x * 256 + threadIdx.x;     // over INTER*DST = 32768
    float carry = 0.0f;
#pragma unroll 4
    for (int c = 0; c < NC; ++c) {
        size_t idx = (size_t)c * (INTER * DST) + i;
        Cin[idx] = carry;
        carry = fmaf(Pbuf[idx], carry, Sbuf[idx]);
    }
}

__global__ __launch_bounds__(256) void ssm_pass3(const f16* __restrict__ dtbh,
                                                 const f16* __restrict__ hh,
                                                 const float* __restrict__ ssm_p,
                                                 const f16* __restrict__ projh,
                                                 const float* __restrict__ A_log,
                                                 const float* __restrict__ Dvec,
                                                 const float* __restrict__ Cin,
                                                 f16* __restrict__ yh)
{
    const int h = blockIdx.x * 256 + threadIdx.x;
    const int c = blockIdx.y;
    const int s0 = c * LCH;

    __shared__ float Bs[LCH][DST];
    __shared__ float Cs[LCH][DST];
    for (int j = threadIdx.x; j < LCH * DST; j += 256) {
        int r = j >> 4, dd = j & 15;
        Bs[r][dd] = ssm_p[(size_t)(s0 + r) * NP + DTR + dd];
        Cs[r][dd] = ssm_p[(size_t)(s0 + r) * NP + DTR + DST + dd];
    }
    __syncthreads();

    float A[DST], st[DST];
    size_t base = ((size_t)c * INTER + h) * DST;
#pragma unroll
    for (int d = 0; d < DST; ++d) {
        A[d] = -__expf(A_log[(size_t)h * DST + d]);
        st[d] = Cin[base + d];
    }
    const float Dv = Dvec[h];

    for (int r = 0; r < LCH; ++r) {
        float dtv = (float)dtbh[(size_t)(s0 + r) * INTER + h];
        float hv  = (float)hh[(size_t)(s0 + r) * INTER + h];
        float g   = (float)projh[(size_t)(s0 + r) * (2 * INTER) + INTER + h];
        float dh = dtv * hv;
        float y = 0.0f;
#pragma unroll
        for (int d = 0; d < DST; ++d) {
            float da = __expf(dtv * A[d]);
            st[d] = fmaf(da, st[d], dh * Bs[r][d]);
            y = fmaf(st[d], Cs[r][d], y);
        }
        y = fmaf(hv, Dv, y);
        yh[(size_t)(s0 + r) * INTER + h] = (f16)(y * siluf_(g));
    }
}

// ---------------------------------------------------------------------------
extern "C" void kernel_launch(void* const* d_in, const int* in_sizes, int n_in,
                              void* d_out, int out_size, void* d_ws, size_t ws_size,
                              hipStream_t stream)
{
    const float* x      = (const float*)d_in[0];
    const float* W_in   = (const float*)d_in[1];
    const float* conv_w = (const float*)d_in[2];
    const float* conv_b = (const float*)d_in[3];
    const float* W_x    = (const float*)d_in[4];
    const float* W_dt   = (const float*)d_in[5];
    const float* b_dt   = (const float*)d_in[6];
    const float* A_log  = (const float*)d_in[7];
    const float* Dv     = (const float*)d_in[8];
    const float* W_out  = (const float*)d_in[9];
    float* out = (float*)d_out;

    float* ws = (float*)d_ws;
    // flat layout, no aliasing (float-element offsets)
    f16*  projh  = (f16*)ws;                     // 8,388,608 halves
    f16*  hh     = (f16*)(ws + 4194304);         // 4,194,304 halves
    f16*  dtbh   = (f16*)(ws + 6291456);         // 4,194,304 halves
    f16*  yh     = (f16*)(ws + 8388608);         // 4,194,304 halves
    f16*  xh     = (f16*)(ws + 10485760);        // 2,097,152 halves
    f16*  W_in_t = (f16*)(ws + 11534336);        // 4,194,304 halves
    f16*  W_out_t= (f16*)(ws + 13631488);        // 2,097,152 halves
    f16*  WxT    = (f16*)(ws + 14680064);        // 196,608 halves
    f16*  tsh    = (f16*)(ws + 14778368);        // 131,072 halves
    f16*  WdtT   = (f16*)(ws + 14843904);        // 131,072 halves
    float* ssm_p = ws + 14909440;                // 196,608 floats
    f16*  parts  = (f16*)(ws + 15106048);        // 3,145,728 halves (f16 now)
    float* Sbuf  = ws + 16678912;                // 2,097,152 floats
    float* Pbuf  = ws + 18776064;                // 2,097,152 floats
    float* Cin   = ws + 20873216;                // 2,097,152 floats

    // 0) all conversions/transposes in one kernel
    prep_all<<<8512, 256, 0, stream>>>(x, W_in, W_out, W_x, W_dt,
                                       xh, W_in_t, W_out_t, WxT, WdtT);

    // 1) proj = x @ W_in (2048 x 4096 x 1024), f16 MFMA -> f16 output
    gemm_f16mfma<128, 128, HID, f16><<<512, 256, 0, stream>>>(
        xh, W_in_t, projh, 2 * INTER, 32);

    // 2) h = silu(conv(raw) + b) -> f16
    conv_silu<<<(SEQ * INTER / 8) / 256, 256, 0, stream>>>(projh, conv_w, conv_b, hh);

    // 3) ssm_p = h @ W_x (split-K=16 MFMA, f16 partials + vector reduce)
    hwx_mfma<<<256, 256, 0, stream>>>(hh, WxT, parts);
    reduce_partials<<<(SEQ * NP / 8) / 256, 256, 0, stream>>>(parts, ssm_p, tsh);

    // 4) dt = softplus(ts @ W_dt + b_dt) -> f16
    dt_mfma<<<256, 256, 0, stream>>>(tsh, WdtT, b_dt, dtbh);

    // 5) chunked SSM scan, fused epilogue -> y f16
    ssm_pass1<<<dim3(INTER / 256, NC), 256, 0, stream>>>(dtbh, hh, ssm_p, A_log, Sbuf, Pbuf);
    ssm_pass2<<<(INTER * DST) / 256, 256, 0, stream>>>(Sbuf, Pbuf, Cin);
    ssm_pass3<<<dim3(INTER / 256, NC), 256, 0, stream>>>(dtbh, hh, ssm_p, projh, A_log, Dv, Cin, yh);

    // 6) out = y @ W_out (2048 x 1024 x 2048), f16 MFMA -> f32 output
    gemm_f16mfma<64, 128, INTER, float><<<256, 256, 0, stream>>>(
        yh, W_out_t, out, HID, 8);
}

// Round 7
// 183.032 us; speedup vs baseline: 1.0111x; 1.0111x over previous
//
#include <hip/hip_runtime.h>
#include <math.h>

#define SEQ   2048
#define HID   1024
#define INTER 2048
#define DST   16
#define DTR   64
#define NP    96   // DTR + 2*DST
#define NC    128  // scan chunks
#define LCH   16   // steps per chunk (NC*LCH == SEQ)
#define KS    16   // split-K factor for h @ W_x

typedef _Float16 f16;
typedef _Float16 f16x8 __attribute__((ext_vector_type(8)));
typedef _Float16 f16x4v __attribute__((ext_vector_type(4)));
typedef float f32x4 __attribute__((ext_vector_type(4)));

__device__ __forceinline__ float sigmoidf_(float x) { return 1.0f / (1.0f + expf(-x)); }
__device__ __forceinline__ float siluf_(float x)    { return x * sigmoidf_(x); }
__device__ __forceinline__ float softplusf_(float x){ return (x > 20.0f) ? x : log1pf(expf(x)); }

// XCD-aware bijective block swizzle (requires nwg % 8 == 0).
__device__ __forceinline__ int xcd_swz(int bid, int nwg)
{
    int cpx = nwg >> 3;
    return (bid & 7) * cpx + (bid >> 3);
}

// ---------------------------------------------------------------------------
// prep_all: one kernel doing x->f16 + all 4 weight transposes (f32 -> f16^T).
// Block ranges: [0,2048) cvt x | [2048,6144) W_in | [6144,8192) W_out
//               [8192,8384) W_x | [8384,8512) W_dt
// ---------------------------------------------------------------------------
__device__ __forceinline__ void tile_transpose(const float* __restrict__ W,
                                               f16* __restrict__ Wt,
                                               int K, int N, int bx, int by, int tid)
{
    __shared__ float t[32][33];
    const int n0 = bx * 32, k0 = by * 32;
    const int j = tid & 31, i0 = tid >> 5;   // i0: 0..7
#pragma unroll
    for (int r = 0; r < 4; ++r)
        t[i0 + r * 8][j] = W[(size_t)(k0 + i0 + r * 8) * N + n0 + j];
    __syncthreads();
#pragma unroll
    for (int r = 0; r < 4; ++r)
        Wt[(size_t)(n0 + i0 + r * 8) * K + k0 + j] = (f16)t[j][i0 + r * 8];
}

__global__ __launch_bounds__(256) void prep_all(const float* __restrict__ x,
                                                const float* __restrict__ W_in,
                                                const float* __restrict__ W_out,
                                                const float* __restrict__ W_x,
                                                const float* __restrict__ W_dt,
                                                f16* __restrict__ xh,
                                                f16* __restrict__ W_in_t,
                                                f16* __restrict__ W_out_t,
                                                f16* __restrict__ WxT,
                                                f16* __restrict__ WdtT)
{
    const int bid = blockIdx.x, tid = threadIdx.x;
    if (bid < 2048) {
        int i = (bid * 256 + tid) * 4;
        float4 v = *(const float4*)&x[i];
        f16x4v o;
        o.x = (f16)v.x; o.y = (f16)v.y; o.z = (f16)v.z; o.w = (f16)v.w;
        *(f16x4v*)&xh[i] = o;
    } else if (bid < 6144) {
        int t = bid - 2048;                       // W_in: K=1024, N=4096
        tile_transpose(W_in, W_in_t, HID, 4096, t & 127, t >> 7, tid);
    } else if (bid < 8192) {
        int t = bid - 6144;                       // W_out: K=2048, N=1024
        tile_transpose(W_out, W_out_t, INTER, HID, t & 31, t >> 5, tid);
    } else if (bid < 8384) {
        int t = bid - 8192;                       // W_x: K=2048, N=96
        tile_transpose(W_x, WxT, INTER, NP, t % 3, t / 3, tid);
    } else {
        int t = bid - 8384;                       // W_dt: K=64, N=2048
        tile_transpose(W_dt, WdtT, DTR, INTER, t & 63, t >> 6, tid);
    }
}

// ---------------------------------------------------------------------------
// MFMA f16 GEMM: C[M,N] OutT = Ah[M,K] f16 @ Bt[N,K]^T f16.
// m97 structure: BK=64, 4 waves (2x2), global_load_lds width 16, linear LDS.
// ---------------------------------------------------------------------------
template<int BM, int BN, int KK, typename OutT>
__global__ __launch_bounds__(256) void gemm_f16mfma(const f16* __restrict__ Ah,
                                                    const f16* __restrict__ Bt,
                                                    OutT* __restrict__ C,
                                                    int N, int nbx)
{
    constexpr int BK = 64;
    __shared__ __align__(16) f16 As[BM * BK];
    __shared__ __align__(16) f16 Bs[BN * BK];

    const int tile = xcd_swz(blockIdx.x, gridDim.x);
    const int bx = tile % nbx, by = tile / nbx;

    const int tid = threadIdx.x;
    const int wid = tid >> 6, lane = tid & 63;
    const int wr = wid >> 1, wc = wid & 1;
    const int m0 = by * BM, n0 = bx * BN;
    const int l15 = lane & 15, lhi = lane >> 4;

    constexpr int MR = BM / 32;
    constexpr int NR = BN / 32;

    f32x4 acc[MR][NR] = {};

    for (int k0 = 0; k0 < KK; k0 += BK) {
        constexpr int CA = BM * BK * 2 / 1024;
#pragma unroll
        for (int c0 = 0; c0 < CA; c0 += 4) {
            int c = c0 + wid;
            int e = c * 64 + lane;
            int row = e >> 3, seg = e & 7;
            __builtin_amdgcn_global_load_lds(
                (const __attribute__((address_space(1))) unsigned int*)
                    (Ah + (size_t)(m0 + row) * KK + k0 + seg * 8),
                (__attribute__((address_space(3))) unsigned int*)(As + c * 512),
                16, 0, 0);
        }
        constexpr int CB = BN * BK * 2 / 1024;
#pragma unroll
        for (int c0 = 0; c0 < CB; c0 += 4) {
            int c = c0 + wid;
            int e = c * 64 + lane;
            int row = e >> 3, seg = e & 7;
            __builtin_amdgcn_global_load_lds(
                (const __attribute__((address_space(1))) unsigned int*)
                    (Bt + (size_t)(n0 + row) * KK + k0 + seg * 8),
                (__attribute__((address_space(3))) unsigned int*)(Bs + c * 512),
                16, 0, 0);
        }
        __syncthreads();

#pragma unroll
        for (int kk = 0; kk < BK; kk += 32) {
            f16x8 af[MR], bf[NR];
#pragma unroll
            for (int i = 0; i < MR; ++i)
                af[i] = *(const f16x8*)&As[(wr * (BM / 2) + i * 16 + l15) * BK + kk + lhi * 8];
#pragma unroll
            for (int n = 0; n < NR; ++n)
                bf[n] = *(const f16x8*)&Bs[(wc * (BN / 2) + n * 16 + l15) * BK + kk + lhi * 8];
#pragma unroll
            for (int i = 0; i < MR; ++i)
#pragma unroll
                for (int n = 0; n < NR; ++n)
                    acc[i][n] = __builtin_amdgcn_mfma_f32_16x16x32_f16(af[i], bf[n], acc[i][n], 0, 0, 0);
        }
        __syncthreads();
    }

    // C/D map: col = lane&15, row = (lane>>4)*4 + reg
#pragma unroll
    for (int i = 0; i < MR; ++i)
#pragma unroll
        for (int n = 0; n < NR; ++n)
#pragma unroll
            for (int r = 0; r < 4; ++r)
                C[(size_t)(m0 + wr * (BM / 2) + i * 16 + lhi * 4 + r) * N
                  + n0 + wc * (BN / 2) + n * 16 + l15] = (OutT)acc[i][n][r];
}

// ---------------------------------------------------------------------------
// h @ W_x split-K MFMA: partials[ks][SEQ][96] (f16) = h[:,ks*128:+128] @ WxT^T
// ---------------------------------------------------------------------------
__global__ __launch_bounds__(256) void hwx_mfma(const f16* __restrict__ hh,
                                                const f16* __restrict__ WxT,
                                                f16* __restrict__ partials)
{
    constexpr int BM = 128, BN = 96, BK = 64;
    __shared__ __align__(16) f16 As[BM * BK];
    __shared__ __align__(16) f16 Bs[BN * BK];

    const int tile = xcd_swz(blockIdx.x, gridDim.x);
    const int bxm = tile & 15, ks = tile >> 4;

    const int tid = threadIdx.x;
    const int wid = tid >> 6, lane = tid & 63;
    const int wr = wid >> 1, wc = wid & 1;
    const int m0 = bxm * BM;
    const int l15 = lane & 15, lhi = lane >> 4;

    constexpr int MR = 4, NR = 3;
    f32x4 acc[MR][NR] = {};

    for (int k0 = ks * 128; k0 < ks * 128 + 128; k0 += BK) {
#pragma unroll
        for (int c0 = 0; c0 < 16; c0 += 4) {
            int c = c0 + wid;
            int e = c * 64 + lane;
            int row = e >> 3, seg = e & 7;
            __builtin_amdgcn_global_load_lds(
                (const __attribute__((address_space(1))) unsigned int*)
                    (hh + (size_t)(m0 + row) * INTER + k0 + seg * 8),
                (__attribute__((address_space(3))) unsigned int*)(As + c * 512),
                16, 0, 0);
        }
#pragma unroll
        for (int c0 = 0; c0 < 12; c0 += 4) {
            int c = c0 + wid;
            int e = c * 64 + lane;
            int row = e >> 3, seg = e & 7;
            __builtin_amdgcn_global_load_lds(
                (const __attribute__((address_space(1))) unsigned int*)
                    (WxT + (size_t)row * INTER + k0 + seg * 8),
                (__attribute__((address_space(3))) unsigned int*)(Bs + c * 512),
                16, 0, 0);
        }
        __syncthreads();

#pragma unroll
        for (int kk = 0; kk < BK; kk += 32) {
            f16x8 af[MR], bf[NR];
#pragma unroll
            for (int i = 0; i < MR; ++i)
                af[i] = *(const f16x8*)&As[(wr * 64 + i * 16 + l15) * BK + kk + lhi * 8];
#pragma unroll
            for (int n = 0; n < NR; ++n)
                bf[n] = *(const f16x8*)&Bs[(wc * 48 + n * 16 + l15) * BK + kk + lhi * 8];
#pragma unroll
            for (int i = 0; i < MR; ++i)
#pragma unroll
                for (int n = 0; n < NR; ++n)
                    acc[i][n] = __builtin_amdgcn_mfma_f32_16x16x32_f16(af[i], bf[n], acc[i][n], 0, 0, 0);
        }
        __syncthreads();
    }

    f16* P = partials + (size_t)ks * (SEQ * NP);
#pragma unroll
    for (int i = 0; i < MR; ++i)
#pragma unroll
        for (int n = 0; n < NR; ++n)
#pragma unroll
            for (int r = 0; r < 4; ++r)
                P[(size_t)(m0 + wr * 64 + i * 16 + lhi * 4 + r) * NP
                  + wc * 48 + n * 16 + l15] = (f16)acc[i][n][r];
}

// ---------------------------------------------------------------------------
// reduce 16 f16 partial planes -> ssm_p (B,C cols, f32) + tsh (ts cols, f16).
// ---------------------------------------------------------------------------
__global__ __launch_bounds__(256) void reduce_partials(const f16* __restrict__ partials,
                                                       float* __restrict__ ssm_p,
                                                       f16* __restrict__ tsh)
{
    int t = blockIdx.x * 256 + threadIdx.x;     // over SEQ*NP/8 = 24576
    int i8 = t * 8;
    int s = i8 / NP, j0 = i8 % NP;
    float a[8] = {};
#pragma unroll
    for (int c = 0; c < KS; ++c) {
        f16x8 v = *(const f16x8*)&partials[(size_t)c * (SEQ * NP) + i8];
#pragma unroll
        for (int j = 0; j < 8; ++j) a[j] += (float)v[j];
    }
    if (j0 < DTR) {
        f16x8 o;
#pragma unroll
        for (int j = 0; j < 8; ++j) o[j] = (f16)a[j];
        *(f16x8*)&tsh[(size_t)s * DTR + j0] = o;
    } else {
        *(float4*)&ssm_p[(size_t)s * NP + j0]     = make_float4(a[0], a[1], a[2], a[3]);
        *(float4*)&ssm_p[(size_t)s * NP + j0 + 4] = make_float4(a[4], a[5], a[6], a[7]);
    }
}

// ---------------------------------------------------------------------------
// dt = softplus(ts @ W_dt + b_dt), f16 MFMA, K=64 single staging iteration.
// ---------------------------------------------------------------------------
__global__ __launch_bounds__(256) void dt_mfma(const f16* __restrict__ tsh,
                                               const f16* __restrict__ WdtT,
                                               const float* __restrict__ bdt,
                                               f16* __restrict__ dtbh)
{
    constexpr int BM = 128, BN = 128, BK = 64;
    __shared__ __align__(16) f16 As[BM * BK];
    __shared__ __align__(16) f16 Bs[BN * BK];

    const int tile = xcd_swz(blockIdx.x, gridDim.x);
    const int bx = tile & 15, by = tile >> 4;

    const int tid = threadIdx.x;
    const int wid = tid >> 6, lane = tid & 63;
    const int wr = wid >> 1, wc = wid & 1;
    const int m0 = by * BM, n0 = bx * BN;
    const int l15 = lane & 15, lhi = lane >> 4;

    constexpr int MR = 4, NR = 4;
    f32x4 acc[MR][NR] = {};

#pragma unroll
    for (int c0 = 0; c0 < 16; c0 += 4) {
        int c = c0 + wid;
        int e = c * 64 + lane;
        int row = e >> 3, seg = e & 7;
        __builtin_amdgcn_global_load_lds(
            (const __attribute__((address_space(1))) unsigned int*)
                (tsh + (size_t)(m0 + row) * DTR + seg * 8),
            (__attribute__((address_space(3))) unsigned int*)(As + c * 512),
            16, 0, 0);
        __builtin_amdgcn_global_load_lds(
            (const __attribute__((address_space(1))) unsigned int*)
                (WdtT + (size_t)(n0 + row) * DTR + seg * 8),
            (__attribute__((address_space(3))) unsigned int*)(Bs + c * 512),
            16, 0, 0);
    }
    __syncthreads();

#pragma unroll
    for (int kk = 0; kk < 64; kk += 32) {
        f16x8 af[MR], bf[NR];
#pragma unroll
        for (int i = 0; i < MR; ++i)
            af[i] = *(const f16x8*)&As[(wr * 64 + i * 16 + l15) * BK + kk + lhi * 8];
#pragma unroll
        for (int n = 0; n < NR; ++n)
            bf[n] = *(const f16x8*)&Bs[(wc * 64 + n * 16 + l15) * BK + kk + lhi * 8];
#pragma unroll
        for (int i = 0; i < MR; ++i)
#pragma unroll
            for (int n = 0; n < NR; ++n)
                acc[i][n] = __builtin_amdgcn_mfma_f32_16x16x32_f16(af[i], bf[n], acc[i][n], 0, 0, 0);
    }

#pragma unroll
    for (int i = 0; i < MR; ++i)
#pragma unroll
        for (int n = 0; n < NR; ++n) {
            int col = n0 + wc * 64 + n * 16 + l15;
            float bv = bdt[col];
#pragma unroll
            for (int r = 0; r < 4; ++r)
                dtbh[(size_t)(m0 + wr * 64 + i * 16 + lhi * 4 + r) * INTER + col] =
                    (f16)softplusf_(acc[i][n][r] + bv);
        }
}

// ---------------------------------------------------------------------------
// Depthwise causal conv (K=4) + bias + SiLU; f16 in (proj raw half), f16 out.
// ---------------------------------------------------------------------------
__global__ __launch_bounds__(256) void conv_silu(const f16* __restrict__ projh,
                                                 const float* __restrict__ cw,
                                                 const float* __restrict__ cb,
                                                 f16* __restrict__ hh)
{
    int idx = blockIdx.x * 256 + threadIdx.x;   // over SEQ*INTER/8
    int c8 = (idx & (INTER / 8 - 1)) * 8;
    int s = idx >> 8;
    float acc[8];
#pragma unroll
    for (int j = 0; j < 8; ++j) acc[j] = cb[c8 + j];
#pragma unroll
    for (int k = 0; k < 4; ++k) {
        int sp = s + k - 3;
        if (sp >= 0) {
            f16x8 p = *(const f16x8*)&projh[(size_t)sp * (2 * INTER) + c8];
#pragma unroll
            for (int j = 0; j < 8; ++j)
                acc[j] = fmaf((float)p[j], cw[k * INTER + c8 + j], acc[j]);
        }
    }
    f16x8 o;
#pragma unroll
    for (int j = 0; j < 8; ++j) o[j] = (f16)siluf_(acc[j]);
    *(f16x8*)&hh[(size_t)idx * 8] = o;
}

// ---------------------------------------------------------------------------
// Chunked parallel scan (pass1/2/3); f16 dt/h/gate inputs, f16 y output.
// NC=128 chunks of LCH=16 steps; pass1 P via exp(A * sum(dt)).
// ---------------------------------------------------------------------------
__global__ __launch_bounds__(256) void ssm_pass1(const f16* __restrict__ dtbh,
                                                 const f16* __restrict__ hh,
                                                 const float* __restrict__ ssm_p,
                                                 const float* __restrict__ A_log,
                                                 float* __restrict__ Sbuf,
                                                 float* __restrict__ Pbuf)
{
    const int h = blockIdx.x * 256 + threadIdx.x;
    const int c = blockIdx.y;
    const int s0 = c * LCH;

    __shared__ float Bs[LCH][DST];
    for (int j = threadIdx.x; j < LCH * DST; j += 256) {
        int r = j >> 4, dd = j & 15;
        Bs[r][dd] = ssm_p[(size_t)(s0 + r) * NP + DTR + dd];
    }
    __syncthreads();

    float A[DST], st[DST];
#pragma unroll
    for (int d = 0; d < DST; ++d) {
        A[d] = -__expf(A_log[(size_t)h * DST + d]);
        st[d] = 0.0f;
    }

    float dtsum = 0.0f;
    for (int r = 0; r < LCH; ++r) {
        float dtv = (float)dtbh[(size_t)(s0 + r) * INTER + h];
        float hv  = (float)hh[(size_t)(s0 + r) * INTER + h];
        float dh = dtv * hv;
        dtsum += dtv;
#pragma unroll
        for (int d = 0; d < DST; ++d) {
            float da = __expf(dtv * A[d]);
            st[d] = fmaf(da, st[d], dh * Bs[r][d]);
        }
    }

    size_t base = ((size_t)c * INTER + h) * DST;
#pragma unroll
    for (int d = 0; d < DST; d += 4) {
        *(float4*)&Sbuf[base + d] = make_float4(st[d], st[d+1], st[d+2], st[d+3]);
        float4 p4;
        p4.x = __expf(A[d]     * dtsum);
        p4.y = __expf(A[d + 1] * dtsum);
        p4.z = __expf(A[d + 2] * dtsum);
        p4.w = __expf(A[d + 3] * dtsum);
        *(float4*)&Pbuf[base + d] = p4;
    }
}

__global__ __launch_bounds__(256) void ssm_pass2(const float* __restrict__ Sbuf,
                                                 const float* __restrict__ Pbuf,
                                                 float* __restrict__ Cin)
{
    int i = blockIdx.x * 256 + threadIdx.x;     // over INTER*DST = 32768
    float carry = 0.0f;
#pragma unroll 8
    for (int c = 0; c < NC; ++c) {
        size_t idx = (size_t)c * (INTER * DST) + i;
        Cin[idx] = carry;
        carry = fmaf(Pbuf[idx], carry, Sbuf[idx]);
    }
}

__global__ __launch_bounds__(256) void ssm_pass3(const f16* __restrict__ dtbh,
                                                 const f16* __restrict__ hh,
                                                 const float* __restrict__ ssm_p,
                                                 const f16* __restrict__ projh,
                                                 const float* __restrict__ A_log,
                                                 const float* __restrict__ Dvec,
                                                 const float* __restrict__ Cin,
                                                 f16* __restrict__ yh)
{
    const int h = blockIdx.x * 256 + threadIdx.x;
    const int c = blockIdx.y;
    const int s0 = c * LCH;

    __shared__ float Bs[LCH][DST];
    __shared__ float Cs[LCH][DST];
    for (int j = threadIdx.x; j < LCH * DST; j += 256) {
        int r = j >> 4, dd = j & 15;
        Bs[r][dd] = ssm_p[(size_t)(s0 + r) * NP + DTR + dd];
        Cs[r][dd] = ssm_p[(size_t)(s0 + r) * NP + DTR + DST + dd];
    }
    __syncthreads();

    float A[DST], st[DST];
    size_t base = ((size_t)c * INTER + h) * DST;
#pragma unroll
    for (int d = 0; d < DST; ++d) {
        A[d] = -__expf(A_log[(size_t)h * DST + d]);
        st[d] = Cin[base + d];
    }
    const float Dv = Dvec[h];

    for (int r = 0; r < LCH; ++r) {
        float dtv = (float)dtbh[(size_t)(s0 + r) * INTER + h];
        float hv  = (float)hh[(size_t)(s0 + r) * INTER + h];
        float g   = (float)projh[(size_t)(s0 + r) * (2 * INTER) + INTER + h];
        float dh = dtv * hv;
        float y = 0.0f;
#pragma unroll
        for (int d = 0; d < DST; ++d) {
            float da = __expf(dtv * A[d]);
            st[d] = fmaf(da, st[d], dh * Bs[r][d]);
            y = fmaf(st[d], Cs[r][d], y);
        }
        y = fmaf(hv, Dv, y);
        yh[(size_t)(s0 + r) * INTER + h] = (f16)(y * siluf_(g));
    }
}

// ---------------------------------------------------------------------------
extern "C" void kernel_launch(void* const* d_in, const int* in_sizes, int n_in,
                              void* d_out, int out_size, void* d_ws, size_t ws_size,
                              hipStream_t stream)
{
    const float* x      = (const float*)d_in[0];
    const float* W_in   = (const float*)d_in[1];
    const float* conv_w = (const float*)d_in[2];
    const float* conv_b = (const float*)d_in[3];
    const float* W_x    = (const float*)d_in[4];
    const float* W_dt   = (const float*)d_in[5];
    const float* b_dt   = (const float*)d_in[6];
    const float* A_log  = (const float*)d_in[7];
    const float* Dv     = (const float*)d_in[8];
    const float* W_out  = (const float*)d_in[9];
    float* out = (float*)d_out;

    float* ws = (float*)d_ws;
    // flat layout, no aliasing (float-element offsets)
    f16*  projh  = (f16*)ws;                     // 8,388,608 halves
    f16*  hh     = (f16*)(ws + 4194304);         // 4,194,304 halves
    f16*  dtbh   = (f16*)(ws + 6291456);         // 4,194,304 halves
    f16*  yh     = (f16*)(ws + 8388608);         // 4,194,304 halves
    f16*  xh     = (f16*)(ws + 10485760);        // 2,097,152 halves
    f16*  W_in_t = (f16*)(ws + 11534336);        // 4,194,304 halves
    f16*  W_out_t= (f16*)(ws + 13631488);        // 2,097,152 halves
    f16*  WxT    = (f16*)(ws + 14680064);        // 196,608 halves
    f16*  tsh    = (f16*)(ws + 14778368);        // 131,072 halves
    f16*  WdtT   = (f16*)(ws + 14843904);        // 131,072 halves
    float* ssm_p = ws + 14909440;                // 196,608 floats
    f16*  parts  = (f16*)(ws + 15106048);        // 3,145,728 halves
    float* Sbuf  = ws + 16678912;                // 4,194,304 floats (NC=128)
    float* Pbuf  = ws + 20873216;                // 4,194,304 floats
    float* Cin   = ws + 25067520;                // 4,194,304 floats

    // 0) all conversions/transposes in one kernel
    prep_all<<<8512, 256, 0, stream>>>(x, W_in, W_out, W_x, W_dt,
                                       xh, W_in_t, W_out_t, WxT, WdtT);

    // 1) proj = x @ W_in (2048 x 4096 x 1024), f16 MFMA -> f16 output
    gemm_f16mfma<128, 128, HID, f16><<<512, 256, 0, stream>>>(
        xh, W_in_t, projh, 2 * INTER, 32);

    // 2) h = silu(conv(raw) + b) -> f16
    conv_silu<<<(SEQ * INTER / 8) / 256, 256, 0, stream>>>(projh, conv_w, conv_b, hh);

    // 3) ssm_p = h @ W_x (split-K=16 MFMA, f16 partials + vector reduce)
    hwx_mfma<<<256, 256, 0, stream>>>(hh, WxT, parts);
    reduce_partials<<<(SEQ * NP / 8) / 256, 256, 0, stream>>>(parts, ssm_p, tsh);

    // 4) dt = softplus(ts @ W_dt + b_dt) -> f16
    dt_mfma<<<256, 256, 0, stream>>>(tsh, WdtT, b_dt, dtbh);

    // 5) chunked SSM scan (NC=128), fused epilogue -> y f16
    ssm_pass1<<<dim3(INTER / 256, NC), 256, 0, stream>>>(dtbh, hh, ssm_p, A_log, Sbuf, Pbuf);
    ssm_pass2<<<(INTER * DST) / 256, 256, 0, stream>>>(Sbuf, Pbuf, Cin);
    ssm_pass3<<<dim3(INTER / 256, NC), 256, 0, stream>>>(dtbh, hh, ssm_p, projh, A_log, Dv, Cin, yh);

    // 6) out = y @ W_out (2048 x 1024 x 2048), f16 MFMA -> f32 output
    gemm_f16mfma<64, 128, INTER, float><<<256, 256, 0, stream>>>(
        yh, W_out_t, out, HID, 8);
}